// Round 13
// baseline (494.449 us; speedup 1.0000x reference)
//
#include <hip/hip_runtime.h>
#include <math.h>

#define KF 4752          // real feature dim: 96 + 96 + 4560
#define KP 4768          // padded to 32*149
#define KSTEPS 149
#define G4 384           // 4*C1 gates
#define NPAIR 4560
#define EPSBN 1e-5f
#define XWHALF 3840000   // 10000*384 floats per K-quarter partial

typedef float f32x4 __attribute__((ext_vector_type(4)));
typedef short s16x8 __attribute__((ext_vector_type(8)));

__device__ __forceinline__ unsigned short f2bf(float x){
  unsigned u = __float_as_uint(x);
  return (unsigned short)((u + 0x7fffu + ((u>>16)&1u)) >> 16);
}
__device__ __forceinline__ float bf2f(unsigned short h){
  return __uint_as_float(((unsigned)h)<<16);
}

__device__ __forceinline__ int seg_start(int s){ return (s<=24)? 6*s : 149 + 6*(s-25); }
__device__ __forceinline__ int seg_len(int s){ return (s==24)?5:6; }

// ---------------- merged precompute: geffT, beffT, W hi/lo split ------------
#define NB_GEFF 1407
#define NB_BEFF 1200
#define NB_WSPL 7152

__global__ __launch_bounds__(256) void kPre(
    const float* bn_g,const float* bn_b,const float* bn_m,const float* bn_v,
    const float* Ap,const float* Ar,const float* Wg,const float* bg,
    const float* bn2_g,const float* bn2_b,const float* bn2_m,const float* bn2_v,
    const float* wih,
    float* geffT, float* beffT, unsigned short* whi, unsigned short* wlo)
{
  int bid = blockIdx.x, tid = threadIdx.x;
  if (bid < NB_GEFF){
    int idx = bid*256 + tid;
    if (idx >= 2*96*25*75) return;
    int cu = idx % 75; int rest = idx/75;
    int v = rest % 25; rest /= 25;
    int o = rest % 96; int m = rest / 96;
    int c = cu/25, u = cu%25;
    int ch = (m*25+u)*3 + c;
    float s1 = bn_g[ch] / sqrtf(bn_v[ch] + EPSBN);
    float s2 = bn2_g[o] / sqrtf(bn2_v[o] + EPSBN);
    float acc = 0.f;
    for (int k=0;k<13;k++){
      float a = Ap[(k*25+v)*25+u] + Ar[(k*25+v)*25+u];
      acc += Wg[o*39 + k*3 + c] * a;
    }
    geffT[((size_t)(m*75+cu))*2400 + v*96 + o] = acc * s1 * s2;
  } else if (bid < NB_GEFF + NB_BEFF){
    int wid  = ((bid-NB_GEFF)*256 + tid) >> 6;
    int lane = tid & 63;
    if (wid >= 2*96*25) return;
    int v = wid % 25; int rest = wid/25; int o = rest % 96; int m = rest/96;
    float acc = 0.f;
    #pragma unroll
    for (int it=0; it<16; ++it){
      int item = it*64 + lane;
      if (item < 975){
        int k = item / 75; int cu = item % 75; int c = cu/25, u = cu%25;
        int ch = (m*25+u)*3 + c;
        float s1 = bn_g[ch] / sqrtf(bn_v[ch] + EPSBN);
        float t1 = bn_b[ch] - bn_m[ch]*s1;
        float a  = Ap[(k*25+v)*25+u] + Ar[(k*25+v)*25+u];
        acc += Wg[o*39 + k*3 + c] * a * t1;
      }
    }
    #pragma unroll
    for (int off=32; off; off>>=1) acc += __shfl_down(acc, off);
    if (lane == 0){
      acc += bg[o];
      float s2 = bn2_g[o]/sqrtf(bn2_v[o]+EPSBN);
      beffT[m*2400 + v*96 + o] = s2*(acc - bn2_m[o]) + bn2_b[o];
    }
  } else {
    int idx = (bid - NB_GEFF - NB_BEFF)*256 + tid;
    if (idx >= G4*KP) return;
    int g = idx / KP, k = idx % KP;
    float v = (k < KF) ? wih[(size_t)g*KF + k] : 0.f;
    unsigned short h = f2bf(v);
    whi[idx] = h;
    wlo[idx] = f2bf(v - bf2f(h));
  }
}

// ---------------- p[b=nm*25+v][t][o] = relu(sum_cu geff*x + beff) -----------
#define TTILE 10
__global__ __launch_bounds__(256) void kP(const float* x, const float* geffT, const float* beffT, float* p){
  int nm = blockIdx.y;            // 0..7
  int t0 = blockIdx.x * TTILE;
  int m  = nm % 2;
  __shared__ float xs[75*TTILE];
  int tid = threadIdx.x;
  for (int li = tid; li < 75*TTILE; li += 256){
    int u = li % 25; int rest = li/25; int tt = rest % TTILE; int c = rest / TTILE;
    xs[(c*25+u)*TTILE + tt] = x[(((size_t)nm*3 + c)*300 + (t0+tt))*25 + u];
  }
  __syncthreads();
  const float* gT = geffT + (size_t)m*75*2400;
  for (int ow = tid; ow < 2400; ow += 256){
    int o = ow % 96, v = ow / 96;
    float b = beffT[m*2400 + ow];
    float acc[TTILE];
    #pragma unroll
    for (int t=0;t<TTILE;t++) acc[t] = b;
    for (int cu=0; cu<75; cu++){
      float gv = gT[(size_t)cu*2400 + ow];   // coalesced across lanes
      #pragma unroll
      for (int t=0;t<TTILE;t++) acc[t] += gv * xs[cu*TTILE+t];
    }
    #pragma unroll
    for (int t=0;t<TTILE;t++)
      p[((size_t)(nm*25+v)*300 + t0+t)*96 + o] = fmaxf(acc[t], 0.f);
  }
}

// ---------------- feat rows -> split bf16 hi/lo (outer-product v2) ----------
// 2 rows per block. 272 6x6 (i,j)-tiles over 256 threads (94% active; R12's
// single-row version idled 47%). Each tile: 24 LDS b32 per l (12 broadcast
// i-side, 12 conflict-free j-side) for 36 pairs -> ~0.67 LDS instr/pair vs 24
// in the pairs version. No qbuf staging / extra barrier / pack pass: q values
// go straight to global as scalar 2B hi/lo stores (L2 write-combines).
// Math identical to R12's verified version (absmax 0.0).
__global__ __launch_bounds__(256) void kFeat(const float* p,
                                             unsigned short* fhi, unsigned short* flo, int row0){
  __shared__ float psL[2][6][96];
  __shared__ float dsL[2][6][96];
  int tid = threadIdx.x;
  if (tid < 192){
    int rr = tid / 96, c = tid % 96;
    int row = row0 + blockIdx.x*2 + rr;
    int b = row / 50, s = row % 50;
    int S = seg_start(s), len = seg_len(s);
    size_t base = (size_t)(blockIdx.x*2 + rr) * KP;
    float pv[7];
    #pragma unroll
    for (int l=0;l<7;l++) pv[l] = p[((size_t)b*300 + S + l)*96 + c];
    float run = 0.f;
    #pragma unroll
    for (int l=0;l<6;l++){
      float d = (l < len) ? (pv[l+1]-pv[l]) : 0.f;
      psL[rr][l][c] = run; dsL[rr][l][c] = d; run += d;
    }
    unsigned short h0 = f2bf(pv[0]);
    fhi[base + c] = h0; flo[base + c] = f2bf(pv[0] - bf2f(h0));
    unsigned short h1 = f2bf(run);
    fhi[base + 96 + c] = h1; flo[base + 96 + c] = f2bf(run - bf2f(h1));
  } else if (tid < 224){
    int z = tid - 192;                // zero the K-pad, both rows
    int rr = z >> 4, c = KF + (z & 15);
    size_t base = (size_t)(blockIdx.x*2 + rr) * KP;
    fhi[base + c] = 0; flo[base + c] = 0;
  }
  __syncthreads();
  for (int tt = tid; tt < 272; tt += 256){
    int rr = (tt >= 136) ? 1 : 0;
    int tix = tt - 136*rr;
    int ti = 0, rem = tix;
    while (rem >= 16 - ti){ rem -= 16 - ti; ti++; }
    int tj = ti + rem;
    int i0 = ti*6, j0 = tj*6;
    size_t base = (size_t)(blockIdx.x*2 + rr) * KP + 192;
    float q[6][6];
    #pragma unroll
    for (int a=0;a<6;a++)
      #pragma unroll
      for (int e=0;e<6;e++) q[a][e] = 0.f;
    #pragma unroll
    for (int l=0;l<6;l++){
      float pi[6], di[6], pj[6], dj[6];
      #pragma unroll
      for (int a=0;a<6;a++){
        pi[a] = psL[rr][l][i0+a]; di[a] = dsL[rr][l][i0+a];
        pj[a] = psL[rr][l][j0+a]; dj[a] = dsL[rr][l][j0+a];
      }
      #pragma unroll
      for (int a=0;a<6;a++)
        #pragma unroll
        for (int e=0;e<6;e++)
          q[a][e] += pi[a]*dj[e] - pj[e]*di[a];
    }
    #pragma unroll
    for (int a=0;a<6;a++){
      int i = i0 + a;
      int kb = i*95 - (i*(i-1))/2 - i - 1;   // k = kb + j for j>i
      #pragma unroll
      for (int e=0;e<6;e++){
        int j = j0 + e;
        if (j > i){
          float qq = 0.5f*q[a][e];
          unsigned short h = f2bf(qq);
          fhi[base + kb + j] = h;
          flo[base + kb + j] = f2bf(qq - bf2f(h));
        }
      }
    }
  }
}

// ---------------- MFMA split-bf16 GEMM: xw_partial = feat . W_ih^T ----------
// R8-exact structure (measured 139 us): tile 128x192, BK=32, 4 waves of 64x96,
// double-buffered 80 KiB LDS, __syncthreads pipelining (the barrier's vmcnt(0)
// drain covers the PREVIOUS iteration's prefetch -> depth-1 pipeline), grid
// (col 2, zz 4, mblk) = 632 blocks.
__device__ __forceinline__ void gload16(const void* g, void* l){
  __builtin_amdgcn_global_load_lds(
      (const __attribute__((address_space(1))) void*)g,
      (__attribute__((address_space(3))) void*)l, 16, 0, 0);
}

__global__ __launch_bounds__(256) void kGemm(
    const unsigned short* __restrict__ fhi, const unsigned short* __restrict__ flo,
    const unsigned short* __restrict__ whi, const unsigned short* __restrict__ wlo,
    float* __restrict__ xw, int chunkRow0, int nrows)
{
  // LDS buffer layout (shorts): Ah[0,4096) Al[4096,8192) Bh[8192,14336) Bl[14336,20480)
  __shared__ unsigned short lds[2][20480];   // 80 KiB
  int tid  = threadIdx.x;
  int lane = tid & 63, w = tid >> 6;
  int colBase = blockIdx.x * 192;
  int zz      = blockIdx.y;                  // 0..3 K-quarter
  int mblk    = blockIdx.z;
  int zbase   = (zz==0) ? 0 : (38 + 37*(zz-1));
  int zSteps  = (zz==0) ? 38 : 37;           // 38+37+37+37 = 149

  // staging: 2560 16B-chunks, 10 per thread; LDS dest linear, global src
  // granule-swizzled (involution g ^= (row>>1)&3) so ds_read_b128 is ~2-way.
  const unsigned short* gptr[10];
  int ldsOff[10];
  #pragma unroll
  for (int q=0;q<10;q++){
    int c = (w*10 + q)*64 + lane;
    const unsigned short* bp; int rr;
    if (c < 512)        { rr = c;        bp = fhi + (size_t)(mblk*128 + (rr>>2))*KP; }
    else if (c < 1024)  { rr = c-512;    bp = flo + (size_t)(mblk*128 + (rr>>2))*KP; }
    else if (c < 1792)  { rr = c-1024;   bp = whi + (size_t)(colBase  + (rr>>2))*KP; }
    else                { rr = c-1792;   bp = wlo + (size_t)(colBase  + (rr>>2))*KP; }
    int row = rr>>2, gl = rr&3;
    int gs = gl ^ ((row>>1)&3);
    gptr[q]  = bp + gs*8;
    ldsOff[q] = (w*10 + q)*512;
  }

  // frag ds_read offsets (shorts)
  int wm = w & 1, wn = w >> 1;
  int gsel = lane >> 4;
  int aoff[4], boff[6];
  #pragma unroll
  for (int fm=0; fm<4; fm++){
    int r = wm*64 + fm*16 + (lane&15);
    aoff[fm] = r*32 + ((gsel ^ ((r>>1)&3))*8);
  }
  #pragma unroll
  for (int fn=0; fn<6; fn++){
    int r = wn*96 + fn*16 + (lane&15);
    boff[fn] = 8192 + r*32 + ((gsel ^ ((r>>1)&3))*8);
  }

  f32x4 acc[4][6];
  #pragma unroll
  for (int fm=0;fm<4;fm++)
    #pragma unroll
    for (int fn=0;fn<6;fn++) acc[fm][fn] = (f32x4){0.f,0.f,0.f,0.f};

  // prologue stage
  #pragma unroll
  for (int q=0;q<10;q++) gload16(gptr[q] + (size_t)zbase*32, &lds[0][ldsOff[q]]);

  int cur = 0;
  for (int t=0; t<zSteps; ++t){
    __syncthreads();                       // drains vmcnt: buf[cur] ready
    if (t+1 < zSteps){
      size_t ko = (size_t)(zbase + t + 1)*32;
      #pragma unroll
      for (int q=0;q<10;q++) gload16(gptr[q] + ko, &lds[cur^1][ldsOff[q]]);
    }
    const unsigned short* L = lds[cur];
    s16x8 ah[4], al[4], bh[6], bl[6];
    #pragma unroll
    for (int fm=0;fm<4;fm++){
      ah[fm] = *(const s16x8*)(L + aoff[fm]);
      al[fm] = *(const s16x8*)(L + aoff[fm] + 4096);
    }
    #pragma unroll
    for (int fn=0;fn<6;fn++){
      bh[fn] = *(const s16x8*)(L + boff[fn]);
      bl[fn] = *(const s16x8*)(L + boff[fn] + 6144);
    }
    #pragma unroll
    for (int fm=0;fm<4;fm++)
      #pragma unroll
      for (int fn=0;fn<6;fn++){
        acc[fm][fn] = __builtin_amdgcn_mfma_f32_16x16x32_bf16(ah[fm], bh[fn], acc[fm][fn], 0,0,0);
        acc[fm][fn] = __builtin_amdgcn_mfma_f32_16x16x32_bf16(ah[fm], bl[fn], acc[fm][fn], 0,0,0);
        acc[fm][fn] = __builtin_amdgcn_mfma_f32_16x16x32_bf16(al[fm], bh[fn], acc[fm][fn], 0,0,0);
      }
    cur ^= 1;
  }

  // epilogue: C/D layout col=lane&15, row=(lane>>4)*4+reg (m89/m91)
  int rl = (lane>>4)*4, cl = lane&15;
  float* outp = xw + (size_t)zz*XWHALF;
  #pragma unroll
  for (int fm=0;fm<4;fm++){
    #pragma unroll
    for (int fn=0;fn<6;fn++){
      int gr0 = mblk*128 + wm*64 + fm*16 + rl;
      int gc  = colBase + wn*96 + fn*16 + cl;
      f32x4 v = acc[fm][fn];
      #pragma unroll
      for (int r=0;r<4;r++){
        int gr = gr0 + r;
        if (gr < nrows)
          outp[(size_t)(chunkRow0 + gr)*G4 + gc] = v[r];
      }
    }
  }
}

// ---------------- LSTM: 192 threads, 2 gates each; sums 4 K-partials -------
__global__ __launch_bounds__(192) void kLstm(const float* xw, const float* whh,
                                             const float* bih, const float* bhh, float* hsum){
  int b = blockIdx.x;
  int t = threadIdx.x;           // 0..191
  int gA = t;                    // t<96: i_t ; else f_{t-96}
  int gB = t + 192;              // t<96: g_t ; else o_{t-96}
  __shared__ __align__(16) float h_s[96];
  __shared__ float gbuf[384];
  float wA[96], wB[96];
  #pragma unroll
  for (int k=0;k<96;k++){ wA[k] = whh[(size_t)gA*96 + k]; wB[k] = whh[(size_t)gB*96 + k]; }
  float bA = bih[gA] + bhh[gA];
  float bB = bih[gB] + bhh[gB];
  float cval = 0.f, hacc = 0.f;
  if (t < 96) h_s[t] = 0.f;
  __syncthreads();
  const float* xr = xw + (size_t)b*50*G4;
  for (int st=0; st<50; st++){
    int o = st*G4;
    float aA = xr[o+gA] + xr[XWHALF+o+gA] + xr[2*(size_t)XWHALF+o+gA]
             + xr[3*(size_t)XWHALF+o+gA] + bA;
    float aB = xr[o+gB] + xr[XWHALF+o+gB] + xr[2*(size_t)XWHALF+o+gB]
             + xr[3*(size_t)XWHALF+o+gB] + bB;
    #pragma unroll
    for (int k=0;k<96;k+=4){
      float4 h4 = *(const float4*)&h_s[k];
      aA += wA[k]*h4.x + wA[k+1]*h4.y + wA[k+2]*h4.z + wA[k+3]*h4.w;
      aB += wB[k]*h4.x + wB[k+1]*h4.y + wB[k+2]*h4.z + wB[k+3]*h4.w;
    }
    gbuf[gA] = aA; gbuf[gB] = aB;
    __syncthreads();
    if (t < 96){
      float ig = gbuf[t], fg = gbuf[96+t], gg = gbuf[192+t], og = gbuf[288+t];
      float si = 1.f/(1.f+expf(-ig));
      float sf = 1.f/(1.f+expf(-fg));
      float so = 1.f/(1.f+expf(-og));
      cval = sf*cval + si*tanhf(gg);
      float h = so * tanhf(cval);
      h_s[t] = h;
      hacc += h;
    }
    __syncthreads();
  }
  if (t < 96) hsum[(size_t)b*96 + t] = hacc;
}

// ---------------- head ------------------------------------------------------
__global__ void kOut(const float* hsum, const float* wfc, const float* bfc, float* out){
  int n = blockIdx.x;
  __shared__ float pool[96];
  int tid = threadIdx.x;   // 128
  if (tid < 96){
    float a = 0.f;
    for (int mv=0; mv<50; mv++) a += hsum[((size_t)(n*50 + mv))*96 + tid];
    pool[tid] = a / 2500.f;
  }
  __syncthreads();
  if (tid < 60){
    float a = bfc[tid];
    for (int o=0;o<96;o++) a += pool[o]*wfc[tid*96+o];
    out[n*60+tid] = a;
  }
}

extern "C" void kernel_launch(void* const* d_in, const int* in_sizes, int n_in,
                              void* d_out, int out_size, void* d_ws, size_t ws_size,
                              hipStream_t stream){
  const float* x     = (const float*)d_in[0];
  const float* bn_g  = (const float*)d_in[1];
  const float* bn_b  = (const float*)d_in[2];
  const float* bn_m  = (const float*)d_in[3];
  const float* bn_v  = (const float*)d_in[4];
  const float* Ap    = (const float*)d_in[5];
  const float* Ar    = (const float*)d_in[6];
  const float* Wg    = (const float*)d_in[7];
  const float* bg    = (const float*)d_in[8];
  const float* bn2_g = (const float*)d_in[9];
  const float* bn2_b = (const float*)d_in[10];
  const float* bn2_m = (const float*)d_in[11];
  const float* bn2_v = (const float*)d_in[12];
  const float* wih   = (const float*)d_in[13];
  const float* whh   = (const float*)d_in[14];
  const float* bih   = (const float*)d_in[15];
  const float* bhh   = (const float*)d_in[16];
  const float* wfc   = (const float*)d_in[17];
  const float* bfc   = (const float*)d_in[18];
  float* out = (float*)d_out;

  float* ws    = (float*)d_ws;
  float* geffT = ws;                        // 360,000
  float* beffT = geffT + 360000;            // 4,800
  float* pbuf  = beffT + 4800;              // 5,760,000
  float* xw    = pbuf + 5760000;            // 15,360,000 (four K-quarter partials)
  float* hsum  = xw + 4*(size_t)XWHALF;     // 19,200
  unsigned short* whiP = (unsigned short*)(hsum + 19200);   // 384*4768 shorts
  unsigned short* wloP = whiP + (size_t)G4*KP;
  unsigned short* fhi  = wloP + (size_t)G4*KP;              // chunk*KP shorts
  size_t fixedFloats = 360000u + 4800u + 5760000u + 4u*(size_t)XWHALF + 19200u
                     + (size_t)G4*KP;       // W hi+lo = 2*(G4*KP) shorts = G4*KP floats
  long long availB = (long long)ws_size - (long long)(fixedFloats*4);
  long long perUnit = 128LL*KP*4;           // bytes per 128 rows (hi+lo bf16)
  long long units = (availB > 0) ? availB/perUnit : 1;
  if (units < 1)  units = 1;
  if (units > 79) units = 79;
  int chunk = (int)units * 128;
  unsigned short* flo = fhi + (size_t)chunk*KP;

  kPre<<<NB_GEFF+NB_BEFF+NB_WSPL, 256, 0, stream>>>(
      bn_g, bn_b, bn_m, bn_v, Ap, Ar, Wg, bg, bn2_g, bn2_b, bn2_m, bn2_v,
      wih, geffT, beffT, whiP, wloP);
  kP<<<dim3(30, 8), 256, 0, stream>>>(x, geffT, beffT, pbuf);

  for (int r0 = 0; r0 < 10000; r0 += chunk){
    int nr = 10000 - r0; if (nr > chunk) nr = chunk;
    kFeat<<<nr/2, 256, 0, stream>>>(pbuf, fhi, flo, r0);
    kGemm<<<dim3(2, 4, (nr + 127)/128), 256, 0, stream>>>(fhi, flo, whiP, wloP, xw, r0, nr);
  }

  kLstm<<<200, 192, 0, stream>>>(xw, whh, bih, bhh, hsum);
  kOut<<<4, 128, 0, stream>>>(hsum, wfc, bfc, out);
}

// Round 14
// 430.399 us; speedup vs baseline: 1.1488x; 1.1488x over previous
//
#include <hip/hip_runtime.h>
#include <math.h>

#define KF 4752          // real feature dim: 96 + 96 + 4560
#define KP 4768          // padded to 32*149
#define KSTEPS 149
#define G4 384           // 4*C1 gates
#define NPAIR 4560
#define EPSBN 1e-5f
#define XWHALF 3840000   // 10000*384 floats per K-quarter partial

typedef float f32x4 __attribute__((ext_vector_type(4)));
typedef short s16x8 __attribute__((ext_vector_type(8)));

__device__ __forceinline__ unsigned short f2bf(float x){
  unsigned u = __float_as_uint(x);
  return (unsigned short)((u + 0x7fffu + ((u>>16)&1u)) >> 16);
}
__device__ __forceinline__ float bf2f(unsigned short h){
  return __uint_as_float(((unsigned)h)<<16);
}

__device__ __forceinline__ int seg_start(int s){ return (s<=24)? 6*s : 149 + 6*(s-25); }
__device__ __forceinline__ int seg_len(int s){ return (s==24)?5:6; }

// ---------------- merged precompute: geffT, beffT, W hi/lo split ------------
#define NB_GEFF 1407
#define NB_BEFF 1200
#define NB_WSPL 7152

__global__ __launch_bounds__(256) void kPre(
    const float* bn_g,const float* bn_b,const float* bn_m,const float* bn_v,
    const float* Ap,const float* Ar,const float* Wg,const float* bg,
    const float* bn2_g,const float* bn2_b,const float* bn2_m,const float* bn2_v,
    const float* wih,
    float* geffT, float* beffT, unsigned short* whi, unsigned short* wlo)
{
  int bid = blockIdx.x, tid = threadIdx.x;
  if (bid < NB_GEFF){
    int idx = bid*256 + tid;
    if (idx >= 2*96*25*75) return;
    int cu = idx % 75; int rest = idx/75;
    int v = rest % 25; rest /= 25;
    int o = rest % 96; int m = rest / 96;
    int c = cu/25, u = cu%25;
    int ch = (m*25+u)*3 + c;
    float s1 = bn_g[ch] / sqrtf(bn_v[ch] + EPSBN);
    float s2 = bn2_g[o] / sqrtf(bn2_v[o] + EPSBN);
    float acc = 0.f;
    for (int k=0;k<13;k++){
      float a = Ap[(k*25+v)*25+u] + Ar[(k*25+v)*25+u];
      acc += Wg[o*39 + k*3 + c] * a;
    }
    geffT[((size_t)(m*75+cu))*2400 + v*96 + o] = acc * s1 * s2;
  } else if (bid < NB_GEFF + NB_BEFF){
    int wid  = ((bid-NB_GEFF)*256 + tid) >> 6;
    int lane = tid & 63;
    if (wid >= 2*96*25) return;
    int v = wid % 25; int rest = wid/25; int o = rest % 96; int m = rest/96;
    float acc = 0.f;
    #pragma unroll
    for (int it=0; it<16; ++it){
      int item = it*64 + lane;
      if (item < 975){
        int k = item / 75; int cu = item % 75; int c = cu/25, u = cu%25;
        int ch = (m*25+u)*3 + c;
        float s1 = bn_g[ch] / sqrtf(bn_v[ch] + EPSBN);
        float t1 = bn_b[ch] - bn_m[ch]*s1;
        float a  = Ap[(k*25+v)*25+u] + Ar[(k*25+v)*25+u];
        acc += Wg[o*39 + k*3 + c] * a * t1;
      }
    }
    #pragma unroll
    for (int off=32; off; off>>=1) acc += __shfl_down(acc, off);
    if (lane == 0){
      acc += bg[o];
      float s2 = bn2_g[o]/sqrtf(bn2_v[o]+EPSBN);
      beffT[m*2400 + v*96 + o] = s2*(acc - bn2_m[o]) + bn2_b[o];
    }
  } else {
    int idx = (bid - NB_GEFF - NB_BEFF)*256 + tid;
    if (idx >= G4*KP) return;
    int g = idx / KP, k = idx % KP;
    float v = (k < KF) ? wih[(size_t)g*KF + k] : 0.f;
    unsigned short h = f2bf(v);
    whi[idx] = h;
    wlo[idx] = f2bf(v - bf2f(h));
  }
}

// ---------------- p[b=nm*25+v][t][o] = relu(sum_cu geff*x + beff) -----------
#define TTILE 10
__global__ __launch_bounds__(256) void kP(const float* x, const float* geffT, const float* beffT, float* p){
  int nm = blockIdx.y;            // 0..7
  int t0 = blockIdx.x * TTILE;
  int m  = nm % 2;
  __shared__ float xs[75*TTILE];
  int tid = threadIdx.x;
  for (int li = tid; li < 75*TTILE; li += 256){
    int u = li % 25; int rest = li/25; int tt = rest % TTILE; int c = rest / TTILE;
    xs[(c*25+u)*TTILE + tt] = x[(((size_t)nm*3 + c)*300 + (t0+tt))*25 + u];
  }
  __syncthreads();
  const float* gT = geffT + (size_t)m*75*2400;
  for (int ow = tid; ow < 2400; ow += 256){
    int o = ow % 96, v = ow / 96;
    float b = beffT[m*2400 + ow];
    float acc[TTILE];
    #pragma unroll
    for (int t=0;t<TTILE;t++) acc[t] = b;
    for (int cu=0; cu<75; cu++){
      float gv = gT[(size_t)cu*2400 + ow];   // coalesced across lanes
      #pragma unroll
      for (int t=0;t<TTILE;t++) acc[t] += gv * xs[cu*TTILE+t];
    }
    #pragma unroll
    for (int t=0;t<TTILE;t++)
      p[((size_t)(nm*25+v)*300 + t0+t)*96 + o] = fmaxf(acc[t], 0.f);
  }
}

// ---------------- feat rows -> split bf16 hi/lo (outer-product v3) ----------
// v2's register-tiled compute + coalesced store path. 2 rows/block, 272 6x6
// tiles across 256 threads. Compute phase: 24 conflict-free LDS b32 per l per
// tile (6*ti mod 32 all-distinct). Each q packs to u32 (hi | lo<<16) staged in
// LDS qpk (36 cheap scalar LDS writes/tile). Final pass: 8 consecutive u32 per
// thread -> two coalesced 16B s16x8 stores (fhi, flo). Fixes v2's 91M
// scattered 2B global stores (the R13 regression) while keeping the 5.6x
// LDS-read reduction vs the pairs version. Math identical (absmax 0.0).
__global__ __launch_bounds__(256) void kFeat(const float* p,
                                             unsigned short* fhi, unsigned short* flo, int row0){
  __shared__ float psL[2][6][96];
  __shared__ float dsL[2][6][96];
  __shared__ unsigned qpk[2][NPAIR];
  int tid = threadIdx.x;
  if (tid < 192){
    int rr = tid / 96, c = tid % 96;
    int row = row0 + blockIdx.x*2 + rr;
    int b = row / 50, s = row % 50;
    int S = seg_start(s), len = seg_len(s);
    size_t base = (size_t)(blockIdx.x*2 + rr) * KP;
    float pv[7];
    #pragma unroll
    for (int l=0;l<7;l++) pv[l] = p[((size_t)b*300 + S + l)*96 + c];
    float run = 0.f;
    #pragma unroll
    for (int l=0;l<6;l++){
      float d = (l < len) ? (pv[l+1]-pv[l]) : 0.f;
      psL[rr][l][c] = run; dsL[rr][l][c] = d; run += d;
    }
    unsigned short h0 = f2bf(pv[0]);
    fhi[base + c] = h0; flo[base + c] = f2bf(pv[0] - bf2f(h0));
    unsigned short h1 = f2bf(run);
    fhi[base + 96 + c] = h1; flo[base + 96 + c] = f2bf(run - bf2f(h1));
  } else if (tid < 224){
    int z = tid - 192;                // zero the K-pad, both rows
    int rr = z >> 4, c = KF + (z & 15);
    size_t base = (size_t)(blockIdx.x*2 + rr) * KP;
    fhi[base + c] = 0; flo[base + c] = 0;
  }
  __syncthreads();
  for (int tt = tid; tt < 272; tt += 256){
    int rr = (tt >= 136) ? 1 : 0;
    int tix = tt - 136*rr;
    int ti = 0, rem = tix;
    while (rem >= 16 - ti){ rem -= 16 - ti; ti++; }
    int tj = ti + rem;
    int i0 = ti*6, j0 = tj*6;
    float q[6][6];
    #pragma unroll
    for (int a=0;a<6;a++)
      #pragma unroll
      for (int e=0;e<6;e++) q[a][e] = 0.f;
    #pragma unroll
    for (int l=0;l<6;l++){
      float pi[6], di[6], pj[6], dj[6];
      #pragma unroll
      for (int a=0;a<6;a++){
        pi[a] = psL[rr][l][i0+a]; di[a] = dsL[rr][l][i0+a];
        pj[a] = psL[rr][l][j0+a]; dj[a] = dsL[rr][l][j0+a];
      }
      #pragma unroll
      for (int a=0;a<6;a++)
        #pragma unroll
        for (int e=0;e<6;e++)
          q[a][e] += pi[a]*dj[e] - pj[e]*di[a];
    }
    #pragma unroll
    for (int a=0;a<6;a++){
      int i = i0 + a;
      int kb = i*95 - (i*(i-1))/2 - i - 1;   // k = kb + j for j>i
      #pragma unroll
      for (int e=0;e<6;e++){
        int j = j0 + e;
        if (j > i){
          float qq = 0.5f*q[a][e];
          unsigned short h = f2bf(qq);
          unsigned short lo = f2bf(qq - bf2f(h));
          qpk[rr][kb + j] = (unsigned)h | ((unsigned)lo << 16);
        }
      }
    }
  }
  __syncthreads();
  for (int g8 = tid; g8 < 2*(NPAIR/8); g8 += 256){   // 1140 groups of 8
    int rr = (g8 >= NPAIR/8) ? 1 : 0;
    int idx = g8 - (NPAIR/8)*rr;
    size_t base = (size_t)(blockIdx.x*2 + rr) * KP + 192;
    unsigned qp[8];
    #pragma unroll
    for (int e=0;e<8;e++) qp[e] = qpk[rr][idx*8 + e];
    s16x8 vh, vl;
    #pragma unroll
    for (int e=0;e<8;e++){
      vh[e] = (short)(qp[e] & 0xffffu);
      vl[e] = (short)(qp[e] >> 16);
    }
    *(s16x8*)(fhi + base + idx*8) = vh;
    *(s16x8*)(flo + base + idx*8) = vl;
  }
}

// ---------------- MFMA split-bf16 GEMM: xw_partial = feat . W_ih^T ----------
// R8-exact structure (measured 137-139 us): tile 128x192, BK=32, 4 waves of
// 64x96, double-buffered 80 KiB LDS, __syncthreads pipelining, grid
// (col 2, zz 4, mblk) = 632 blocks.
__device__ __forceinline__ void gload16(const void* g, void* l){
  __builtin_amdgcn_global_load_lds(
      (const __attribute__((address_space(1))) void*)g,
      (__attribute__((address_space(3))) void*)l, 16, 0, 0);
}

__global__ __launch_bounds__(256) void kGemm(
    const unsigned short* __restrict__ fhi, const unsigned short* __restrict__ flo,
    const unsigned short* __restrict__ whi, const unsigned short* __restrict__ wlo,
    float* __restrict__ xw, int chunkRow0, int nrows)
{
  // LDS buffer layout (shorts): Ah[0,4096) Al[4096,8192) Bh[8192,14336) Bl[14336,20480)
  __shared__ unsigned short lds[2][20480];   // 80 KiB
  int tid  = threadIdx.x;
  int lane = tid & 63, w = tid >> 6;
  int colBase = blockIdx.x * 192;
  int zz      = blockIdx.y;                  // 0..3 K-quarter
  int mblk    = blockIdx.z;
  int zbase   = (zz==0) ? 0 : (38 + 37*(zz-1));
  int zSteps  = (zz==0) ? 38 : 37;           // 38+37+37+37 = 149

  // staging: 2560 16B-chunks, 10 per thread; LDS dest linear, global src
  // granule-swizzled (involution g ^= (row>>1)&3) so ds_read_b128 is ~2-way.
  const unsigned short* gptr[10];
  int ldsOff[10];
  #pragma unroll
  for (int q=0;q<10;q++){
    int c = (w*10 + q)*64 + lane;
    const unsigned short* bp; int rr;
    if (c < 512)        { rr = c;        bp = fhi + (size_t)(mblk*128 + (rr>>2))*KP; }
    else if (c < 1024)  { rr = c-512;    bp = flo + (size_t)(mblk*128 + (rr>>2))*KP; }
    else if (c < 1792)  { rr = c-1024;   bp = whi + (size_t)(colBase  + (rr>>2))*KP; }
    else                { rr = c-1792;   bp = wlo + (size_t)(colBase  + (rr>>2))*KP; }
    int row = rr>>2, gl = rr&3;
    int gs = gl ^ ((row>>1)&3);
    gptr[q]  = bp + gs*8;
    ldsOff[q] = (w*10 + q)*512;
  }

  // frag ds_read offsets (shorts)
  int wm = w & 1, wn = w >> 1;
  int gsel = lane >> 4;
  int aoff[4], boff[6];
  #pragma unroll
  for (int fm=0; fm<4; fm++){
    int r = wm*64 + fm*16 + (lane&15);
    aoff[fm] = r*32 + ((gsel ^ ((r>>1)&3))*8);
  }
  #pragma unroll
  for (int fn=0; fn<6; fn++){
    int r = wn*96 + fn*16 + (lane&15);
    boff[fn] = 8192 + r*32 + ((gsel ^ ((r>>1)&3))*8);
  }

  f32x4 acc[4][6];
  #pragma unroll
  for (int fm=0;fm<4;fm++)
    #pragma unroll
    for (int fn=0;fn<6;fn++) acc[fm][fn] = (f32x4){0.f,0.f,0.f,0.f};

  // prologue stage
  #pragma unroll
  for (int q=0;q<10;q++) gload16(gptr[q] + (size_t)zbase*32, &lds[0][ldsOff[q]]);

  int cur = 0;
  for (int t=0; t<zSteps; ++t){
    __syncthreads();                       // drains vmcnt: buf[cur] ready
    if (t+1 < zSteps){
      size_t ko = (size_t)(zbase + t + 1)*32;
      #pragma unroll
      for (int q=0;q<10;q++) gload16(gptr[q] + ko, &lds[cur^1][ldsOff[q]]);
    }
    const unsigned short* L = lds[cur];
    s16x8 ah[4], al[4], bh[6], bl[6];
    #pragma unroll
    for (int fm=0;fm<4;fm++){
      ah[fm] = *(const s16x8*)(L + aoff[fm]);
      al[fm] = *(const s16x8*)(L + aoff[fm] + 4096);
    }
    #pragma unroll
    for (int fn=0;fn<6;fn++){
      bh[fn] = *(const s16x8*)(L + boff[fn]);
      bl[fn] = *(const s16x8*)(L + boff[fn] + 6144);
    }
    #pragma unroll
    for (int fm=0;fm<4;fm++)
      #pragma unroll
      for (int fn=0;fn<6;fn++){
        acc[fm][fn] = __builtin_amdgcn_mfma_f32_16x16x32_bf16(ah[fm], bh[fn], acc[fm][fn], 0,0,0);
        acc[fm][fn] = __builtin_amdgcn_mfma_f32_16x16x32_bf16(ah[fm], bl[fn], acc[fm][fn], 0,0,0);
        acc[fm][fn] = __builtin_amdgcn_mfma_f32_16x16x32_bf16(al[fm], bh[fn], acc[fm][fn], 0,0,0);
      }
    cur ^= 1;
  }

  // epilogue: C/D layout col=lane&15, row=(lane>>4)*4+reg (m89/m91)
  int rl = (lane>>4)*4, cl = lane&15;
  float* outp = xw + (size_t)zz*XWHALF;
  #pragma unroll
  for (int fm=0;fm<4;fm++){
    #pragma unroll
    for (int fn=0;fn<6;fn++){
      int gr0 = mblk*128 + wm*64 + fm*16 + rl;
      int gc  = colBase + wn*96 + fn*16 + cl;
      f32x4 v = acc[fm][fn];
      #pragma unroll
      for (int r=0;r<4;r++){
        int gr = gr0 + r;
        if (gr < nrows)
          outp[(size_t)(chunkRow0 + gr)*G4 + gc] = v[r];
      }
    }
  }
}

// ---------------- LSTM: 192 threads, 2 gates each; sums 4 K-partials -------
__global__ __launch_bounds__(192) void kLstm(const float* xw, const float* whh,
                                             const float* bih, const float* bhh, float* hsum){
  int b = blockIdx.x;
  int t = threadIdx.x;           // 0..191
  int gA = t;                    // t<96: i_t ; else f_{t-96}
  int gB = t + 192;              // t<96: g_t ; else o_{t-96}
  __shared__ __align__(16) float h_s[96];
  __shared__ float gbuf[384];
  float wA[96], wB[96];
  #pragma unroll
  for (int k=0;k<96;k++){ wA[k] = whh[(size_t)gA*96 + k]; wB[k] = whh[(size_t)gB*96 + k]; }
  float bA = bih[gA] + bhh[gA];
  float bB = bih[gB] + bhh[gB];
  float cval = 0.f, hacc = 0.f;
  if (t < 96) h_s[t] = 0.f;
  __syncthreads();
  const float* xr = xw + (size_t)b*50*G4;
  for (int st=0; st<50; st++){
    int o = st*G4;
    float aA = xr[o+gA] + xr[XWHALF+o+gA] + xr[2*(size_t)XWHALF+o+gA]
             + xr[3*(size_t)XWHALF+o+gA] + bA;
    float aB = xr[o+gB] + xr[XWHALF+o+gB] + xr[2*(size_t)XWHALF+o+gB]
             + xr[3*(size_t)XWHALF+o+gB] + bB;
    #pragma unroll
    for (int k=0;k<96;k+=4){
      float4 h4 = *(const float4*)&h_s[k];
      aA += wA[k]*h4.x + wA[k+1]*h4.y + wA[k+2]*h4.z + wA[k+3]*h4.w;
      aB += wB[k]*h4.x + wB[k+1]*h4.y + wB[k+2]*h4.z + wB[k+3]*h4.w;
    }
    gbuf[gA] = aA; gbuf[gB] = aB;
    __syncthreads();
    if (t < 96){
      float ig = gbuf[t], fg = gbuf[96+t], gg = gbuf[192+t], og = gbuf[288+t];
      float si = 1.f/(1.f+expf(-ig));
      float sf = 1.f/(1.f+expf(-fg));
      float so = 1.f/(1.f+expf(-og));
      cval = sf*cval + si*tanhf(gg);
      float h = so * tanhf(cval);
      h_s[t] = h;
      hacc += h;
    }
    __syncthreads();
  }
  if (t < 96) hsum[(size_t)b*96 + t] = hacc;
}

// ---------------- head ------------------------------------------------------
__global__ void kOut(const float* hsum, const float* wfc, const float* bfc, float* out){
  int n = blockIdx.x;
  __shared__ float pool[96];
  int tid = threadIdx.x;   // 128
  if (tid < 96){
    float a = 0.f;
    for (int mv=0; mv<50; mv++) a += hsum[((size_t)(n*50 + mv))*96 + tid];
    pool[tid] = a / 2500.f;
  }
  __syncthreads();
  if (tid < 60){
    float a = bfc[tid];
    for (int o=0;o<96;o++) a += pool[o]*wfc[tid*96+o];
    out[n*60+tid] = a;
  }
}

extern "C" void kernel_launch(void* const* d_in, const int* in_sizes, int n_in,
                              void* d_out, int out_size, void* d_ws, size_t ws_size,
                              hipStream_t stream){
  const float* x     = (const float*)d_in[0];
  const float* bn_g  = (const float*)d_in[1];
  const float* bn_b  = (const float*)d_in[2];
  const float* bn_m  = (const float*)d_in[3];
  const float* bn_v  = (const float*)d_in[4];
  const float* Ap    = (const float*)d_in[5];
  const float* Ar    = (const float*)d_in[6];
  const float* Wg    = (const float*)d_in[7];
  const float* bg    = (const float*)d_in[8];
  const float* bn2_g = (const float*)d_in[9];
  const float* bn2_b = (const float*)d_in[10];
  const float* bn2_m = (const float*)d_in[11];
  const float* bn2_v = (const float*)d_in[12];
  const float* wih   = (const float*)d_in[13];
  const float* whh   = (const float*)d_in[14];
  const float* bih   = (const float*)d_in[15];
  const float* bhh   = (const float*)d_in[16];
  const float* wfc   = (const float*)d_in[17];
  const float* bfc   = (const float*)d_in[18];
  float* out = (float*)d_out;

  float* ws    = (float*)d_ws;
  float* geffT = ws;                        // 360,000
  float* beffT = geffT + 360000;            // 4,800
  float* pbuf  = beffT + 4800;              // 5,760,000
  float* xw    = pbuf + 5760000;            // 15,360,000 (four K-quarter partials)
  float* hsum  = xw + 4*(size_t)XWHALF;     // 19,200
  unsigned short* whiP = (unsigned short*)(hsum + 19200);   // 384*4768 shorts
  unsigned short* wloP = whiP + (size_t)G4*KP;
  unsigned short* fhi  = wloP + (size_t)G4*KP;              // chunk*KP shorts
  size_t fixedFloats = 360000u + 4800u + 5760000u + 4u*(size_t)XWHALF + 19200u
                     + (size_t)G4*KP;       // W hi+lo = 2*(G4*KP) shorts = G4*KP floats
  long long availB = (long long)ws_size - (long long)(fixedFloats*4);
  long long perUnit = 128LL*KP*4;           // bytes per 128 rows (hi+lo bf16)
  long long units = (availB > 0) ? availB/perUnit : 1;
  if (units < 1)  units = 1;
  if (units > 79) units = 79;
  int chunk = (int)units * 128;
  unsigned short* flo = fhi + (size_t)chunk*KP;

  kPre<<<NB_GEFF+NB_BEFF+NB_WSPL, 256, 0, stream>>>(
      bn_g, bn_b, bn_m, bn_v, Ap, Ar, Wg, bg, bn2_g, bn2_b, bn2_m, bn2_v,
      wih, geffT, beffT, whiP, wloP);
  kP<<<dim3(30, 8), 256, 0, stream>>>(x, geffT, beffT, pbuf);

  for (int r0 = 0; r0 < 10000; r0 += chunk){
    int nr = 10000 - r0; if (nr > chunk) nr = chunk;
    kFeat<<<nr/2, 256, 0, stream>>>(pbuf, fhi, flo, r0);
    kGemm<<<dim3(2, 4, (nr + 127)/128), 256, 0, stream>>>(fhi, flo, whiP, wloP, xw, r0, nr);
  }

  kLstm<<<200, 192, 0, stream>>>(xw, whh, bih, bhh, hsum);
  kOut<<<4, 128, 0, stream>>>(hsum, wfc, bfc, out);
}